// Round 10
// baseline (518.810 us; speedup 1.0000x reference)
//
#include <hip/hip_runtime.h>
#include <stdint.h>

// GraphConv (LightGCN-style), exact JAX threefry (partitionable) dropout.
// Round 10: proven round-6 structure (zero-in-init separate from hist, no
// memset, no planar). spmm widened to 16 edge-groups x 4 lanes x 64B/lane:
// 2x edges in flight per iteration (MLP probe vs L3 line-throughput bound).
//
// d_out layout: [N_NODES][N_HOPS+1][D] f32. Slice 0 = concat(user,item),
// slice h+1 = hop h output. Node order user-then-item == output concat order.

static constexpr int kUsers = 50000;
static constexpr int kItems = 100000;
static constexpr int kNodes = kUsers + kItems;   // 150000
static constexpr int kNnz   = 1000000;
static constexpr int kD     = 64;
static constexpr int kHops  = 3;
static constexpr int kRowF  = (kHops + 1) * kD;  // 256 floats per node row

// scan geometry: 147 blocks x 256 threads x 4 elems = 150528 >= kNodes+1
static constexpr int kScanBlocks = 147;
static constexpr int kCntN       = kScanBlocks * 1024;   // 150528

// ---- JAX threefry2x32 (20 rounds), bit-exact -------------------------------
__host__ __device__ inline void tf2x32(uint32_t k0, uint32_t k1,
                                       uint32_t x0, uint32_t x1,
                                       uint32_t &o0, uint32_t &o1) {
  uint32_t ks2 = k0 ^ k1 ^ 0x1BD11BDAu;
  x0 += k0; x1 += k1;
#define TF_R(r) { x0 += x1; x1 = (x1 << (r)) | (x1 >> (32 - (r))); x1 ^= x0; }
  TF_R(13) TF_R(15) TF_R(26) TF_R(6)   x0 += k1;  x1 += ks2 + 1u;
  TF_R(17) TF_R(29) TF_R(16) TF_R(24)  x0 += ks2; x1 += k0 + 2u;
  TF_R(13) TF_R(15) TF_R(26) TF_R(6)   x0 += k0;  x1 += k1 + 3u;
  TF_R(17) TF_R(29) TF_R(16) TF_R(24)  x0 += k1;  x1 += ks2 + 4u;
  TF_R(13) TF_R(15) TF_R(26) TF_R(6)   x0 += ks2; x1 += k0 + 5u;
#undef TF_R
  o0 = x0; o1 = x1;
}

// partitionable random_bits(32): XOR-fold, counter (hi,lo) = (0, i)
__device__ inline uint32_t jax_bits32(uint32_t k0, uint32_t k1, uint32_t i) {
  uint32_t b1, b2;
  tf2x32(k0, k1, 0u, i, b1, b2);
  return b1 ^ b2;
}

__device__ inline float bits_to_unit(uint32_t b) {
  return __uint_as_float((b >> 9) | 0x3f800000u) - 1.0f;
}

// ---- fast path kernels ------------------------------------------------------

// slice0 init + cnt zeroing (separate dispatch BEFORE the atomic histogram)
__global__ __launch_bounds__(256) void init_slice0(
    const float4* __restrict__ user, const float4* __restrict__ item,
    float4* __restrict__ out, int4* __restrict__ cnt4) {
  int i = blockIdx.x * 256 + threadIdx.x;          // grid covers kNodes*16
  if (i < kCntN / 4) cnt4[i] = make_int4(0, 0, 0, 0);
  if (i >= kNodes * 16) return;
  int node = i >> 4, q = i & 15;
  float4 v = (node < kUsers) ? user[node * 16 + q]
                             : item[(node - kUsers) * 16 + q];
  out[(size_t)node * (kRowF / 4) + q] = v;
}

__global__ __launch_bounds__(256) void hist_kernel(
    const int* __restrict__ rows, int* __restrict__ cnt) {
  int e = blockIdx.x * 256 + threadIdx.x;
  if (e >= kNnz) return;
  atomicAdd(&cnt[rows[e]], 1);
}

// scan phase A: per-block totals (1024 elems/block, int4 loads)
__global__ __launch_bounds__(256) void scanA(
    const int* __restrict__ cnt, int* __restrict__ partials) {
  int t = threadIdx.x;
  int4 v = ((const int4*)(cnt + blockIdx.x * 1024))[t];
  int s = v.x + v.y + v.z + v.w;
  __shared__ int sh[256];
  sh[t] = s; __syncthreads();
  for (int off = 128; off > 0; off >>= 1) {
    if (t < off) sh[t] += sh[t + off];
    __syncthreads();
  }
  if (t == 0) partials[blockIdx.x] = sh[0];
}

// scan phase B: exclusive scan of 147 partials (single tiny block)
__global__ __launch_bounds__(256) void scanB(int* __restrict__ partials) {
  int t = threadIdx.x;
  int v = (t < kScanBlocks) ? partials[t] : 0;
  __shared__ int sh[256];
  sh[t] = v; __syncthreads();
  for (int off = 1; off < 256; off <<= 1) {
    int a = (t >= off) ? sh[t - off] : 0;
    __syncthreads();
    sh[t] += a;
    __syncthreads();
  }
  if (t < kScanBlocks) partials[t] = sh[t] - v;    // exclusive
}

// scan phase C: in-place block-local exclusive scan + base (cnt -> cursors X)
__global__ __launch_bounds__(256) void scanC(
    int* __restrict__ cnt, const int* __restrict__ partials) {
  int t = threadIdx.x;
  int4 v = ((const int4*)(cnt + blockIdx.x * 1024))[t];
  int s = v.x + v.y + v.z + v.w;
  __shared__ int sh[256];
  sh[t] = s; __syncthreads();
  for (int off = 1; off < 256; off <<= 1) {
    int a = (t >= off) ? sh[t - off] : 0;
    __syncthreads();
    sh[t] += a;
    __syncthreads();
  }
  int base = partials[blockIdx.x] + sh[t] - s;     // exclusive for elem 4t
  int4 o;
  o.x = base; o.y = base + v.x; o.z = o.y + v.y; o.w = o.z + v.z;
  ((int4*)(cnt + blockIdx.x * 1024))[t] = o;
}

// scatter edges into row-sorted order; ONE 8B record per edge:
//   .x = col | keep0<<29 | keep1<<30 | keep2<<31   (col < 2^18)
//   .y = bits(2 * val)
// After this kernel, X[r] == row_end(r) == row_start(r+1).
__global__ __launch_bounds__(256) void scatter_kernel(
    const int* __restrict__ rows, const int* __restrict__ cols,
    const float* __restrict__ vals, int* __restrict__ X,
    uint2* __restrict__ ed,
    uint32_t e00, uint32_t e01, uint32_t e10, uint32_t e11,
    uint32_t e20, uint32_t e21) {
  int e = blockIdx.x * 256 + threadIdx.x;
  if (e >= kNnz) return;
  int r = rows[e];
  int pos = atomicAdd(&X[r], 1);
  float u0 = bits_to_unit(jax_bits32(e00, e01, (uint32_t)e));
  float u1 = bits_to_unit(jax_bits32(e10, e11, (uint32_t)e));
  float u2 = bits_to_unit(jax_bits32(e20, e21, (uint32_t)e));
  uint32_t packed = (uint32_t)cols[e]
                  | ((0.5f + u0 >= 1.0f) ? (1u << 29) : 0u)
                  | ((0.5f + u1 >= 1.0f) ? (1u << 30) : 0u)
                  | ((0.5f + u2 >= 1.0f) ? (1u << 31) : 0u);
  ed[pos] = make_uint2(packed, __float_as_uint(vals[e] * 2.0f));
}

// pull SpMM: one wave per TWO consecutive rows; 16 edge-groups x 4 lanes per
// row, 64B (4x float4) per lane -> 16 edges in flight per iteration.
__global__ __launch_bounds__(256) void csr_spmm(
    const int* __restrict__ X, const uint2* __restrict__ ed,
    float* __restrict__ out, int hop, uint32_t km0, uint32_t km1) {
  int pair = blockIdx.x * 4 + (threadIdx.x >> 6);
  int rA = pair * 2;
  if (rA >= kNodes) return;
  int lane = threadIdx.x & 63;
  int g = lane >> 2, q = lane & 3;                 // group (0..15), sub-lane
  int sA = (rA == 0) ? 0 : X[rA - 1];
  int tA = X[rA];
  int tB = X[rA + 1];                              // sB == tA
  // message-dropout masks up front (overlap with gather latency)
  float uA = bits_to_unit(jax_bits32(km0, km1, (uint32_t)(rA * kD + lane)));
  float uB = bits_to_unit(jax_bits32(km0, km1, (uint32_t)((rA + 1) * kD + lane)));
  float mA = (uA < 0.9f) ? (1.0f / 0.9f) : 0.0f;
  float mB = (uB < 0.9f) ? (1.0f / 0.9f) : 0.0f;
  float4 a[4] = {{0,0,0,0},{0,0,0,0},{0,0,0,0},{0,0,0,0}};
  float4 b[4] = {{0,0,0,0},{0,0,0,0},{0,0,0,0},{0,0,0,0}};
  const float* src = out + (size_t)hop * kD;
  const uint32_t kbit = 1u << (29 + hop);
  int iA = sA + g, iB = tA + g;
  while (iA < tA || iB < tB) {
    if (iA < tA) {
      uint2 m = ed[iA];
      if (m.x & kbit) {
        float v = __uint_as_float(m.y);
        const float4* p = (const float4*)(src + (size_t)(m.x & 0x3FFFFu) * kRowF + (q << 4));
        float4 x0 = p[0], x1 = p[1], x2 = p[2], x3 = p[3];
        a[0].x += v*x0.x; a[0].y += v*x0.y; a[0].z += v*x0.z; a[0].w += v*x0.w;
        a[1].x += v*x1.x; a[1].y += v*x1.y; a[1].z += v*x1.z; a[1].w += v*x1.w;
        a[2].x += v*x2.x; a[2].y += v*x2.y; a[2].z += v*x2.z; a[2].w += v*x2.w;
        a[3].x += v*x3.x; a[3].y += v*x3.y; a[3].z += v*x3.z; a[3].w += v*x3.w;
      }
      iA += 16;
    }
    if (iB < tB) {
      uint2 m = ed[iB];
      if (m.x & kbit) {
        float v = __uint_as_float(m.y);
        const float4* p = (const float4*)(src + (size_t)(m.x & 0x3FFFFu) * kRowF + (q << 4));
        float4 x0 = p[0], x1 = p[1], x2 = p[2], x3 = p[3];
        b[0].x += v*x0.x; b[0].y += v*x0.y; b[0].z += v*x0.z; b[0].w += v*x0.w;
        b[1].x += v*x1.x; b[1].y += v*x1.y; b[1].z += v*x1.z; b[1].w += v*x1.w;
        b[2].x += v*x2.x; b[2].y += v*x2.y; b[2].z += v*x2.z; b[2].w += v*x2.w;
        b[3].x += v*x3.x; b[3].y += v*x3.y; b[3].z += v*x3.z; b[3].w += v*x3.w;
      }
      iB += 16;
    }
  }
  // reduce the 16 edge-groups (lane bits 2..5) for both rows
#pragma unroll
  for (int msk = 4; msk <= 32; msk <<= 1) {
#pragma unroll
    for (int k = 0; k < 4; ++k) {
      a[k].x += __shfl_xor(a[k].x, msk); a[k].y += __shfl_xor(a[k].y, msk);
      a[k].z += __shfl_xor(a[k].z, msk); a[k].w += __shfl_xor(a[k].w, msk);
      b[k].x += __shfl_xor(b[k].x, msk); b[k].y += __shfl_xor(b[k].y, msk);
      b[k].z += __shfl_xor(b[k].z, msk); b[k].w += __shfl_xor(b[k].w, msk);
    }
  }
  // writers: group 0 lanes (q) -> row rA dims [16q,16q+16); group 1 -> row rB.
  // masks shuffled from owner lanes (lane = dim).
  float w[16];
#pragma unroll
  for (int j = 0; j < 16; ++j) {
    float wA = __shfl(mA, (q << 4) + j);
    float wB = __shfl(mB, (q << 4) + j);
    w[j] = (g == 0) ? wA : wB;
  }
  if (g < 2) {
    int r = rA + g;
    const float4* acc = (g == 0) ? a : b;
    float4* dst = (float4*)(out + (size_t)r * kRowF + (hop + 1) * kD + (q << 4));
#pragma unroll
    for (int k = 0; k < 4; ++k) {
      dst[k] = make_float4(acc[k].x * w[4*k+0], acc[k].y * w[4*k+1],
                           acc[k].z * w[4*k+2], acc[k].w * w[4*k+3]);
    }
  }
}

// ---- fallback (round-2, proven) kernels -------------------------------------
__global__ __launch_bounds__(256) void init_full(
    const float4* __restrict__ user, const float4* __restrict__ item,
    float4* __restrict__ out) {
  int i = blockIdx.x * 256 + threadIdx.x;
  if (i >= kNodes * 16) return;
  int node = i >> 4, q = i & 15;
  float4 v = (node < kUsers) ? user[node * 16 + q]
                             : item[(node - kUsers) * 16 + q];
  float4 z = make_float4(0.f, 0.f, 0.f, 0.f);
  float4* row = out + (size_t)node * (kRowF / 4);
  row[q] = v; row[16 + q] = z; row[32 + q] = z; row[48 + q] = z;
}

__global__ __launch_bounds__(256) void spmm_atomic(
    const int* __restrict__ rows, const int* __restrict__ cols,
    const float* __restrict__ vals, float* __restrict__ out, int hop,
    uint32_t k0, uint32_t k1) {
  int e = (int)((blockIdx.x * 256u + threadIdx.x) >> 6);
  if (e >= kNnz) return;
  int lane = threadIdx.x & 63;
  float u = bits_to_unit(jax_bits32(k0, k1, (uint32_t)e));
  if (!(0.5f + u >= 1.0f)) return;
  float v = vals[e] * 2.0f;
  int r = rows[e], c = cols[e];
  float msg = v * out[(size_t)c * kRowF + hop * kD + lane];
  atomicAdd(&out[(size_t)r * kRowF + (hop + 1) * kD + lane], msg);
}

__global__ __launch_bounds__(256) void mdrop_kernel(
    float* __restrict__ out, int hop, uint32_t k0, uint32_t k1) {
  const int total = kNodes * kD;
  int j = blockIdx.x * 256 + threadIdx.x;
  if (j >= total) return;
  float u = bits_to_unit(jax_bits32(k0, k1, (uint32_t)j));
  int node = j >> 6, d = j & 63;
  size_t idx = (size_t)node * kRowF + (hop + 1) * kD + d;
  float a = out[idx];
  out[idx] = (u < 0.9f) ? a / 0.9f : 0.0f;
}

// ---- launch -----------------------------------------------------------------
extern "C" void kernel_launch(void* const* d_in, const int* in_sizes, int n_in,
                              void* d_out, int out_size, void* d_ws, size_t ws_size,
                              hipStream_t stream) {
  const float* user = (const float*)d_in[0];
  const float* item = (const float*)d_in[1];
  const int*   rows = (const int*)d_in[2];
  const int*   cols = (const int*)d_in[3];
  const float* vals = (const float*)d_in[4];
  float* out = (float*)d_out;

  // host-side key schedule (partitionable split: subkey j = tf(key, 0, j))
  uint32_t k0 = 0u, k1 = 42u;                      // jax.random.key(42)
  uint32_t ke[kHops][2], km[kHops][2];
  for (int hop = 0; hop < kHops; ++hop) {
    uint32_t n0, n1;
    tf2x32(k0, k1, 0u, 0u, n0, n1);
    tf2x32(k0, k1, 0u, 1u, ke[hop][0], ke[hop][1]);
    tf2x32(k0, k1, 0u, 2u, km[hop][0], km[hop][1]);
    k0 = n0; k1 = n1;
  }

  // ws layout (4096-aligned): X | ed | partials
  const size_t x_b   = (size_t)kCntN * 4;          // 602112
  const size_t ed_b  = ((size_t)kNnz * 8 + 4095) & ~(size_t)4095;  // 8003584
  const size_t par_b = 4096;
  const size_t need  = x_b + ed_b + par_b;         // ~8.6 MB

  if (ws_size >= need) {
    char* ws = (char*)d_ws;
    int*   X        = (int*)ws;                    // cnt -> scan -> cursors
    uint2* ed       = (uint2*)(ws + x_b);
    int*   partials = (int*)(ws + x_b + ed_b);

    init_slice0<<<(kNodes * 16 + 255) / 256, 256, 0, stream>>>(
        (const float4*)user, (const float4*)item, (float4*)out, (int4*)X);
    hist_kernel<<<(kNnz + 255) / 256, 256, 0, stream>>>(rows, X);
    scanA<<<kScanBlocks, 256, 0, stream>>>(X, partials);
    scanB<<<1, 256, 0, stream>>>(partials);
    scanC<<<kScanBlocks, 256, 0, stream>>>(X, partials);
    scatter_kernel<<<(kNnz + 255) / 256, 256, 0, stream>>>(
        rows, cols, vals, X, ed,
        ke[0][0], ke[0][1], ke[1][0], ke[1][1], ke[2][0], ke[2][1]);

    const int nPairs = kNodes / 2;                 // 75000
    for (int hop = 0; hop < kHops; ++hop) {
      csr_spmm<<<(nPairs + 3) / 4, 256, 0, stream>>>(
          X, ed, out, hop, km[hop][0], km[hop][1]);
    }
  } else {
    // fallback: proven atomic path
    init_full<<<(kNodes * 16 + 255) / 256, 256, 0, stream>>>(
        (const float4*)user, (const float4*)item, (float4*)out);
    for (int hop = 0; hop < kHops; ++hop) {
      spmm_atomic<<<(kNnz * 64 + 255) / 256, 256, 0, stream>>>(
          rows, cols, vals, out, hop, ke[hop][0], ke[hop][1]);
      mdrop_kernel<<<(kNodes * kD + 255) / 256, 256, 0, stream>>>(
          out, hop, km[hop][0], km[hop][1]);
    }
  }
}

// Round 11
// 303.026 us; speedup vs baseline: 1.7121x; 1.7121x over previous
//
#include <hip/hip_runtime.h>
#include <stdint.h>

// GraphConv (LightGCN-style), exact JAX threefry (partitionable) dropout.
// Round 11: round-6 spmm shape (8 groups x 8 lanes, 2 rows/wave, 3 reduce
// levels) + 2-deep software pipeline in the edge loop: stage 2 ed records
// per row per iteration, issue all gathers before FMAs -> 2x in-flight
// gathers per wave, same shuffle/VALU cost. MLP-vs-line-throughput probe.
//
// d_out layout: [N_NODES][N_HOPS+1][D] f32. Slice 0 = concat(user,item),
// slice h+1 = hop h output. Node order user-then-item == output concat order.

static constexpr int kUsers = 50000;
static constexpr int kItems = 100000;
static constexpr int kNodes = kUsers + kItems;   // 150000
static constexpr int kNnz   = 1000000;
static constexpr int kD     = 64;
static constexpr int kHops  = 3;
static constexpr int kRowF  = (kHops + 1) * kD;  // 256 floats per node row

// scan geometry: 147 blocks x 256 threads x 4 elems = 150528 >= kNodes+1
static constexpr int kScanBlocks = 147;
static constexpr int kCntN       = kScanBlocks * 1024;   // 150528

// ---- JAX threefry2x32 (20 rounds), bit-exact -------------------------------
__host__ __device__ inline void tf2x32(uint32_t k0, uint32_t k1,
                                       uint32_t x0, uint32_t x1,
                                       uint32_t &o0, uint32_t &o1) {
  uint32_t ks2 = k0 ^ k1 ^ 0x1BD11BDAu;
  x0 += k0; x1 += k1;
#define TF_R(r) { x0 += x1; x1 = (x1 << (r)) | (x1 >> (32 - (r))); x1 ^= x0; }
  TF_R(13) TF_R(15) TF_R(26) TF_R(6)   x0 += k1;  x1 += ks2 + 1u;
  TF_R(17) TF_R(29) TF_R(16) TF_R(24)  x0 += ks2; x1 += k0 + 2u;
  TF_R(13) TF_R(15) TF_R(26) TF_R(6)   x0 += k0;  x1 += k1 + 3u;
  TF_R(17) TF_R(29) TF_R(16) TF_R(24)  x0 += k1;  x1 += ks2 + 4u;
  TF_R(13) TF_R(15) TF_R(26) TF_R(6)   x0 += ks2; x1 += k0 + 5u;
#undef TF_R
  o0 = x0; o1 = x1;
}

// partitionable random_bits(32): XOR-fold, counter (hi,lo) = (0, i)
__device__ inline uint32_t jax_bits32(uint32_t k0, uint32_t k1, uint32_t i) {
  uint32_t b1, b2;
  tf2x32(k0, k1, 0u, i, b1, b2);
  return b1 ^ b2;
}

__device__ inline float bits_to_unit(uint32_t b) {
  return __uint_as_float((b >> 9) | 0x3f800000u) - 1.0f;
}

// ---- fast path kernels ------------------------------------------------------

// slice0 init + cnt zeroing (separate dispatch BEFORE the atomic histogram)
__global__ __launch_bounds__(256) void init_slice0(
    const float4* __restrict__ user, const float4* __restrict__ item,
    float4* __restrict__ out, int4* __restrict__ cnt4) {
  int i = blockIdx.x * 256 + threadIdx.x;          // grid covers kNodes*16
  if (i < kCntN / 4) cnt4[i] = make_int4(0, 0, 0, 0);
  if (i >= kNodes * 16) return;
  int node = i >> 4, q = i & 15;
  float4 v = (node < kUsers) ? user[node * 16 + q]
                             : item[(node - kUsers) * 16 + q];
  out[(size_t)node * (kRowF / 4) + q] = v;
}

__global__ __launch_bounds__(256) void hist_kernel(
    const int* __restrict__ rows, int* __restrict__ cnt) {
  int e = blockIdx.x * 256 + threadIdx.x;
  if (e >= kNnz) return;
  atomicAdd(&cnt[rows[e]], 1);
}

// scan phase A: per-block totals (1024 elems/block, int4 loads)
__global__ __launch_bounds__(256) void scanA(
    const int* __restrict__ cnt, int* __restrict__ partials) {
  int t = threadIdx.x;
  int4 v = ((const int4*)(cnt + blockIdx.x * 1024))[t];
  int s = v.x + v.y + v.z + v.w;
  __shared__ int sh[256];
  sh[t] = s; __syncthreads();
  for (int off = 128; off > 0; off >>= 1) {
    if (t < off) sh[t] += sh[t + off];
    __syncthreads();
  }
  if (t == 0) partials[blockIdx.x] = sh[0];
}

// scan phase B: exclusive scan of 147 partials (single tiny block)
__global__ __launch_bounds__(256) void scanB(int* __restrict__ partials) {
  int t = threadIdx.x;
  int v = (t < kScanBlocks) ? partials[t] : 0;
  __shared__ int sh[256];
  sh[t] = v; __syncthreads();
  for (int off = 1; off < 256; off <<= 1) {
    int a = (t >= off) ? sh[t - off] : 0;
    __syncthreads();
    sh[t] += a;
    __syncthreads();
  }
  if (t < kScanBlocks) partials[t] = sh[t] - v;    // exclusive
}

// scan phase C: in-place block-local exclusive scan + base (cnt -> cursors X)
__global__ __launch_bounds__(256) void scanC(
    int* __restrict__ cnt, const int* __restrict__ partials) {
  int t = threadIdx.x;
  int4 v = ((const int4*)(cnt + blockIdx.x * 1024))[t];
  int s = v.x + v.y + v.z + v.w;
  __shared__ int sh[256];
  sh[t] = s; __syncthreads();
  for (int off = 1; off < 256; off <<= 1) {
    int a = (t >= off) ? sh[t - off] : 0;
    __syncthreads();
    sh[t] += a;
    __syncthreads();
  }
  int base = partials[blockIdx.x] + sh[t] - s;     // exclusive for elem 4t
  int4 o;
  o.x = base; o.y = base + v.x; o.z = o.y + v.y; o.w = o.z + v.z;
  ((int4*)(cnt + blockIdx.x * 1024))[t] = o;
}

// scatter edges into row-sorted order; ONE 8B record per edge:
//   .x = col | keep0<<29 | keep1<<30 | keep2<<31   (col < 2^18)
//   .y = bits(2 * val)
// After this kernel, X[r] == row_end(r) == row_start(r+1).
__global__ __launch_bounds__(256) void scatter_kernel(
    const int* __restrict__ rows, const int* __restrict__ cols,
    const float* __restrict__ vals, int* __restrict__ X,
    uint2* __restrict__ ed,
    uint32_t e00, uint32_t e01, uint32_t e10, uint32_t e11,
    uint32_t e20, uint32_t e21) {
  int e = blockIdx.x * 256 + threadIdx.x;
  if (e >= kNnz) return;
  int r = rows[e];
  int pos = atomicAdd(&X[r], 1);
  float u0 = bits_to_unit(jax_bits32(e00, e01, (uint32_t)e));
  float u1 = bits_to_unit(jax_bits32(e10, e11, (uint32_t)e));
  float u2 = bits_to_unit(jax_bits32(e20, e21, (uint32_t)e));
  uint32_t packed = (uint32_t)cols[e]
                  | ((0.5f + u0 >= 1.0f) ? (1u << 29) : 0u)
                  | ((0.5f + u1 >= 1.0f) ? (1u << 30) : 0u)
                  | ((0.5f + u2 >= 1.0f) ? (1u << 31) : 0u);
  ed[pos] = make_uint2(packed, __float_as_uint(vals[e] * 2.0f));
}

// pull SpMM: one wave per TWO consecutive rows; 8 edge-groups x 8 lanes per
// row, 2x float4 per lane; edge loop software-pipelined 2-deep per row.
__global__ __launch_bounds__(256) void csr_spmm(
    const int* __restrict__ X, const uint2* __restrict__ ed,
    float* __restrict__ out, int hop, uint32_t km0, uint32_t km1) {
  int pair = blockIdx.x * 4 + (threadIdx.x >> 6);
  int rA = pair * 2;
  if (rA >= kNodes) return;
  int lane = threadIdx.x & 63;
  int g = lane >> 3, q = lane & 7;                 // group, sub-lane
  int sA = (rA == 0) ? 0 : X[rA - 1];
  int tA = X[rA];
  int tB = X[rA + 1];                              // sB == tA
  // message-dropout masks up front (overlap with gather latency)
  float uA = bits_to_unit(jax_bits32(km0, km1, (uint32_t)(rA * kD + lane)));
  float uB = bits_to_unit(jax_bits32(km0, km1, (uint32_t)((rA + 1) * kD + lane)));
  float mA = (uA < 0.9f) ? (1.0f / 0.9f) : 0.0f;
  float mB = (uB < 0.9f) ? (1.0f / 0.9f) : 0.0f;
  float4 a0 = make_float4(0.f, 0.f, 0.f, 0.f);
  float4 a1 = make_float4(0.f, 0.f, 0.f, 0.f);
  float4 b0 = make_float4(0.f, 0.f, 0.f, 0.f);
  float4 b1 = make_float4(0.f, 0.f, 0.f, 0.f);
  const float* src = out + (size_t)hop * kD;
  const uint32_t kbit = 1u << (29 + hop);

#define GATHER_FMA(acc0, acc1, rec)                                         \
  {                                                                          \
    float v = __uint_as_float((rec).y);                                      \
    const float* p = src + (size_t)((rec).x & 0x3FFFFu) * kRowF + (q << 3);  \
    float4 x0 = *(const float4*)p;                                           \
    float4 x1 = *(const float4*)(p + 4);                                     \
    acc0.x += v * x0.x; acc0.y += v * x0.y;                                  \
    acc0.z += v * x0.z; acc0.w += v * x0.w;                                  \
    acc1.x += v * x1.x; acc1.y += v * x1.y;                                  \
    acc1.z += v * x1.z; acc1.w += v * x1.w;                                  \
  }

  int iA = sA + g, iB = tA + g;
  while (iA < tA || iB < tB) {
    // stage up to 4 edge records (2 per row) before any gather-wait
    uint2 eA0, eA1, eB0, eB1;
    const bool hA0 = iA < tA,     hA1 = iA + 8 < tA;
    const bool hB0 = iB < tB,     hB1 = iB + 8 < tB;
    if (hA0) eA0 = ed[iA];
    if (hA1) eA1 = ed[iA + 8];
    if (hB0) eB0 = ed[iB];
    if (hB1) eB1 = ed[iB + 8];
    if (hA0 && (eA0.x & kbit)) GATHER_FMA(a0, a1, eA0);
    if (hA1 && (eA1.x & kbit)) GATHER_FMA(a0, a1, eA1);
    if (hB0 && (eB0.x & kbit)) GATHER_FMA(b0, b1, eB0);
    if (hB1 && (eB1.x & kbit)) GATHER_FMA(b0, b1, eB1);
    iA += 16; iB += 16;
  }
#undef GATHER_FMA

  // reduce the 8 edge-groups (lane bits 3..5) for both rows
#pragma unroll
  for (int msk = 8; msk <= 32; msk <<= 1) {
    a0.x += __shfl_xor(a0.x, msk); a0.y += __shfl_xor(a0.y, msk);
    a0.z += __shfl_xor(a0.z, msk); a0.w += __shfl_xor(a0.w, msk);
    a1.x += __shfl_xor(a1.x, msk); a1.y += __shfl_xor(a1.y, msk);
    a1.z += __shfl_xor(a1.z, msk); a1.w += __shfl_xor(a1.w, msk);
    b0.x += __shfl_xor(b0.x, msk); b0.y += __shfl_xor(b0.y, msk);
    b0.z += __shfl_xor(b0.z, msk); b0.w += __shfl_xor(b0.w, msk);
    b1.x += __shfl_xor(b1.x, msk); b1.y += __shfl_xor(b1.y, msk);
    b1.z += __shfl_xor(b1.z, msk); b1.w += __shfl_xor(b1.w, msk);
  }
  // writers: group 0 -> row rA, group 1 -> row rB; masks shuffled from owners
  float w[8];
#pragma unroll
  for (int j = 0; j < 8; ++j) {
    float wA = __shfl(mA, (q << 3) + j);
    float wB = __shfl(mB, (q << 3) + j);
    w[j] = (g == 0) ? wA : wB;
  }
  if (g < 2) {
    int r = rA + g;
    float4 r0, r1;
    if (g == 0) {
      r0 = make_float4(a0.x * w[0], a0.y * w[1], a0.z * w[2], a0.w * w[3]);
      r1 = make_float4(a1.x * w[4], a1.y * w[5], a1.z * w[6], a1.w * w[7]);
    } else {
      r0 = make_float4(b0.x * w[0], b0.y * w[1], b0.z * w[2], b0.w * w[3]);
      r1 = make_float4(b1.x * w[4], b1.y * w[5], b1.z * w[6], b1.w * w[7]);
    }
    float* dst = out + (size_t)r * kRowF + (hop + 1) * kD + (q << 3);
    *(float4*)dst = r0;
    *(float4*)(dst + 4) = r1;
  }
}

// ---- fallback (round-2, proven) kernels -------------------------------------
__global__ __launch_bounds__(256) void init_full(
    const float4* __restrict__ user, const float4* __restrict__ item,
    float4* __restrict__ out) {
  int i = blockIdx.x * 256 + threadIdx.x;
  if (i >= kNodes * 16) return;
  int node = i >> 4, q = i & 15;
  float4 v = (node < kUsers) ? user[node * 16 + q]
                             : item[(node - kUsers) * 16 + q];
  float4 z = make_float4(0.f, 0.f, 0.f, 0.f);
  float4* row = out + (size_t)node * (kRowF / 4);
  row[q] = v; row[16 + q] = z; row[32 + q] = z; row[48 + q] = z;
}

__global__ __launch_bounds__(256) void spmm_atomic(
    const int* __restrict__ rows, const int* __restrict__ cols,
    const float* __restrict__ vals, float* __restrict__ out, int hop,
    uint32_t k0, uint32_t k1) {
  int e = (int)((blockIdx.x * 256u + threadIdx.x) >> 6);
  if (e >= kNnz) return;
  int lane = threadIdx.x & 63;
  float u = bits_to_unit(jax_bits32(k0, k1, (uint32_t)e));
  if (!(0.5f + u >= 1.0f)) return;
  float v = vals[e] * 2.0f;
  int r = rows[e], c = cols[e];
  float msg = v * out[(size_t)c * kRowF + hop * kD + lane];
  atomicAdd(&out[(size_t)r * kRowF + (hop + 1) * kD + lane], msg);
}

__global__ __launch_bounds__(256) void mdrop_kernel(
    float* __restrict__ out, int hop, uint32_t k0, uint32_t k1) {
  const int total = kNodes * kD;
  int j = blockIdx.x * 256 + threadIdx.x;
  if (j >= total) return;
  float u = bits_to_unit(jax_bits32(k0, k1, (uint32_t)j));
  int node = j >> 6, d = j & 63;
  size_t idx = (size_t)node * kRowF + (hop + 1) * kD + d;
  float a = out[idx];
  out[idx] = (u < 0.9f) ? a / 0.9f : 0.0f;
}

// ---- launch -----------------------------------------------------------------
extern "C" void kernel_launch(void* const* d_in, const int* in_sizes, int n_in,
                              void* d_out, int out_size, void* d_ws, size_t ws_size,
                              hipStream_t stream) {
  const float* user = (const float*)d_in[0];
  const float* item = (const float*)d_in[1];
  const int*   rows = (const int*)d_in[2];
  const int*   cols = (const int*)d_in[3];
  const float* vals = (const float*)d_in[4];
  float* out = (float*)d_out;

  // host-side key schedule (partitionable split: subkey j = tf(key, 0, j))
  uint32_t k0 = 0u, k1 = 42u;                      // jax.random.key(42)
  uint32_t ke[kHops][2], km[kHops][2];
  for (int hop = 0; hop < kHops; ++hop) {
    uint32_t n0, n1;
    tf2x32(k0, k1, 0u, 0u, n0, n1);
    tf2x32(k0, k1, 0u, 1u, ke[hop][0], ke[hop][1]);
    tf2x32(k0, k1, 0u, 2u, km[hop][0], km[hop][1]);
    k0 = n0; k1 = n1;
  }

  // ws layout (4096-aligned): X | ed | partials
  const size_t x_b   = (size_t)kCntN * 4;          // 602112
  const size_t ed_b  = ((size_t)kNnz * 8 + 4095) & ~(size_t)4095;  // 8003584
  const size_t par_b = 4096;
  const size_t need  = x_b + ed_b + par_b;         // ~8.6 MB

  if (ws_size >= need) {
    char* ws = (char*)d_ws;
    int*   X        = (int*)ws;                    // cnt -> scan -> cursors
    uint2* ed       = (uint2*)(ws + x_b);
    int*   partials = (int*)(ws + x_b + ed_b);

    init_slice0<<<(kNodes * 16 + 255) / 256, 256, 0, stream>>>(
        (const float4*)user, (const float4*)item, (float4*)out, (int4*)X);
    hist_kernel<<<(kNnz + 255) / 256, 256, 0, stream>>>(rows, X);
    scanA<<<kScanBlocks, 256, 0, stream>>>(X, partials);
    scanB<<<1, 256, 0, stream>>>(partials);
    scanC<<<kScanBlocks, 256, 0, stream>>>(X, partials);
    scatter_kernel<<<(kNnz + 255) / 256, 256, 0, stream>>>(
        rows, cols, vals, X, ed,
        ke[0][0], ke[0][1], ke[1][0], ke[1][1], ke[2][0], ke[2][1]);

    const int nPairs = kNodes / 2;                 // 75000
    for (int hop = 0; hop < kHops; ++hop) {
      csr_spmm<<<(nPairs + 3) / 4, 256, 0, stream>>>(
          X, ed, out, hop, km[hop][0], km[hop][1]);
    }
  } else {
    // fallback: proven atomic path
    init_full<<<(kNodes * 16 + 255) / 256, 256, 0, stream>>>(
        (const float4*)user, (const float4*)item, (float4*)out);
    for (int hop = 0; hop < kHops; ++hop) {
      spmm_atomic<<<(kNnz * 64 + 255) / 256, 256, 0, stream>>>(
          rows, cols, vals, out, hop, ke[hop][0], ke[hop][1]);
      mdrop_kernel<<<(kNodes * kD + 255) / 256, 256, 0, stream>>>(
          out, hop, km[hop][0], km[hop][1]);
    }
  }
}